// Round 1
// baseline (728.459 us; speedup 1.0000x reference)
//
#include <hip/hip_runtime.h>

// SVD_Layer: out = x @ W + b, W = einsum('ios,sIOS,Sab->iIaoOb', W1,W2,W3).reshape(768,3072)
// Sizes: x(32768,768) f32; W1(8,16,134); W2(134,12,12,134); W3(134,8,16); b(3072); out(32768,3072) f32.
// Strategy: build W in fp32 (2-step contraction), store as bf16 W^T (N-major,K-contig);
// cast x to bf16; run m97-style 128x128/BK32 MFMA GEMM with global_load_lds(16B).

typedef unsigned short u16;
typedef unsigned int   u32;
typedef short s16x8 __attribute__((ext_vector_type(8)));   // 8 bf16 (4 VGPRs), guide §3
typedef float f32x4 __attribute__((ext_vector_type(4)));

__device__ __forceinline__ u16 f2bf(float f) {
  u32 u = __float_as_uint(f);
  u32 r = (u + 0x7FFFu + ((u >> 16) & 1u)) >> 16;   // RNE, finite inputs only
  return (u16)r;
}

__device__ __forceinline__ void gload_lds16(const void* g, void* l) {
  // async 16B/lane global->LDS; LDS dest = wave-uniform base + lane*16
  __builtin_amdgcn_global_load_lds(
      (const __attribute__((address_space(1))) void*)g,
      (__attribute__((address_space(3))) void*)l, 16, 0, 0);
}

// ---------------- kernel 1: x fp32 -> bf16 (8 elems/thread) ----------------
__global__ __launch_bounds__(256) void xconv_kernel(const float* __restrict__ x,
                                                    u16* __restrict__ xb) {
  size_t idx = ((size_t)blockIdx.x * 256 + threadIdx.x) * 8;
  float4 v0 = *(const float4*)(x + idx);
  float4 v1 = *(const float4*)(x + idx + 4);
  uint4 o;
  o.x = (u32)f2bf(v0.x) | ((u32)f2bf(v0.y) << 16);
  o.y = (u32)f2bf(v0.z) | ((u32)f2bf(v0.w) << 16);
  o.z = (u32)f2bf(v1.x) | ((u32)f2bf(v1.y) << 16);
  o.w = (u32)f2bf(v1.z) | ((u32)f2bf(v1.w) << 16);
  *(uint4*)(xb + idx) = o;
}

// ---------------- kernel 2: T1[io][I*1608+O*134+S] = sum_s W1[io*134+s]*W2[s*19296+ios] ----
// grid (76, 4), block 256. Each block: 32 io values (LDS-staged W1 rows) x 256 ios columns.
__global__ __launch_bounds__(256) void a1_kernel(const float* __restrict__ W1,
                                                 const float* __restrict__ W2,
                                                 float* __restrict__ T1) {
  __shared__ float lW1[32 * 136];   // rows padded 134->136 for aligned float4 reads
  const int t = threadIdx.x;
  const int iog = blockIdx.y;               // io base = iog*32
  const int ios = blockIdx.x * 256 + t;     // 0..19455, valid < 19296
  for (int idx = t; idx < 32 * 136; idx += 256) {
    int u = idx / 136, s = idx - u * 136;
    lW1[idx] = (s < 134) ? W1[(size_t)(iog * 32 + u) * 134 + s] : 0.f;
  }
  __syncthreads();
  const bool valid = ios < 19296;
  float acc[32];
#pragma unroll
  for (int u = 0; u < 32; u++) acc[u] = 0.f;
  for (int s4 = 0; s4 < 136; s4 += 4) {
    float wa = (valid && s4 + 0 < 134) ? W2[(size_t)(s4 + 0) * 19296 + ios] : 0.f;
    float wb = (valid && s4 + 1 < 134) ? W2[(size_t)(s4 + 1) * 19296 + ios] : 0.f;
    float wc = (valid && s4 + 2 < 134) ? W2[(size_t)(s4 + 2) * 19296 + ios] : 0.f;
    float wd = (valid && s4 + 3 < 134) ? W2[(size_t)(s4 + 3) * 19296 + ios] : 0.f;
#pragma unroll
    for (int u = 0; u < 32; u++) {
      float4 wv = *(const float4*)&lW1[u * 136 + s4];   // broadcast read
      acc[u] += wv.x * wa + wv.y * wb + wv.z * wc + wv.w * wd;
    }
  }
  if (valid) {
#pragma unroll
    for (int u = 0; u < 32; u++)
      T1[(size_t)(iog * 32 + u) * 19296 + ios] = acc[u];
  }
}

// ---------------- kernel 3: Wt_bf16[col][k] = W[k][col], W = sum_S T1 * W3 ----------------
// grid (128 io, 12 I), block 128 (t = ab = a*16+b). Covers rows i*96+I*8+(0..8), cols o*192+(0..192).
__global__ __launch_bounds__(128) void a2_kernel(const float* __restrict__ T1,
                                                 const float* __restrict__ W3,
                                                 u16* __restrict__ Wt) {
  __shared__ float lT[12 * 136];     // T1 slice [O][S], padded
  __shared__ u16 lOut[192 * 8];      // [O*16+b][a]
  const int t = threadIdx.x;         // 0..127 = a*16+b
  const int io = blockIdx.x;         // 0..127
  const int I = blockIdx.y;          // 0..11
  const int i = io >> 4, o = io & 15;
  const float* src = T1 + (size_t)io * 19296 + (size_t)I * 1608;
  for (int idx = t; idx < 12 * 136; idx += 128) {
    int O = idx / 136, S = idx - O * 136;
    lT[idx] = (S < 134) ? src[O * 134 + S] : 0.f;
  }
  __syncthreads();
  float acc[12];
#pragma unroll
  for (int O = 0; O < 12; O++) acc[O] = 0.f;
  for (int S4 = 0; S4 < 136; S4 += 4) {
    float w0 = (S4 + 0 < 134) ? W3[(S4 + 0) * 128 + t] : 0.f;
    float w1 = (S4 + 1 < 134) ? W3[(S4 + 1) * 128 + t] : 0.f;
    float w2 = (S4 + 2 < 134) ? W3[(S4 + 2) * 128 + t] : 0.f;
    float w3 = (S4 + 3 < 134) ? W3[(S4 + 3) * 128 + t] : 0.f;
#pragma unroll
    for (int O = 0; O < 12; O++) {
      float4 tv = *(const float4*)&lT[O * 136 + S4];   // broadcast read
      acc[O] += tv.x * w0 + tv.y * w1 + tv.z * w2 + tv.w * w3;
    }
  }
  const int a = t >> 4, b = t & 15;
#pragma unroll
  for (int O = 0; O < 12; O++) lOut[(O * 16 + b) * 8 + a] = f2bf(acc[O]);
  __syncthreads();
  for (int rr = t; rr < 192; rr += 128) {     // rr = O*16+b -> one Wt row, 8 contiguous k (=W rows)
    int col = o * 192 + rr;
    *(uint4*)&Wt[(size_t)col * 768 + i * 96 + I * 8] = *(const uint4*)&lOut[rr * 8];
  }
}

// ---------------- kernel 4: C = Xb(32768x768) * Wt^T + bias, bf16 MFMA ----------------
// 128x128 tile, BK=32, 4 waves each 64x64 (4x4 of 16x16x32), global_load_lds 16B staging.
__global__ __launch_bounds__(256) void gemm_kernel(const u16* __restrict__ A,
                                                   const u16* __restrict__ Bt,
                                                   const float* __restrict__ bias,
                                                   float* __restrict__ C) {
  __shared__ u16 lA[128 * 32];
  __shared__ u16 lB[128 * 32];
  const int t = threadIdx.x;
  const int wave = t >> 6, lane = t & 63;
  const int q = lane >> 4, l16 = lane & 15;
  const int wr = wave >> 1, wc = wave & 1;
  const int blockN = blockIdx.x * 128, blockM = blockIdx.y * 128;

  f32x4 acc[4][4];
  const f32x4 z = {0.f, 0.f, 0.f, 0.f};
#pragma unroll
  for (int mi = 0; mi < 4; mi++)
#pragma unroll
    for (int ni = 0; ni < 4; ni++) acc[mi][ni] = z;

  const int rowA = t >> 2;            // 0..63
  const int kc = (t & 3) * 8;
  const u16* gA = A + (size_t)(blockM + rowA) * 768 + kc;
  const u16* gB = Bt + (size_t)(blockN + rowA) * 768 + kc;
  u16* lAw0 = lA + wave * 512;        // wave-uniform LDS bases (64 chunks * 8 u16)
  u16* lAw1 = lA + 2048 + wave * 512;
  u16* lBw0 = lB + wave * 512;
  u16* lBw1 = lB + 2048 + wave * 512;

  for (int kt = 0; kt < 24; ++kt) {
    const int k0 = kt * 32;
    gload_lds16(gA + k0, lAw0);
    gload_lds16(gA + 64 * 768 + k0, lAw1);
    gload_lds16(gB + k0, lBw0);
    gload_lds16(gB + 64 * 768 + k0, lBw1);
    __syncthreads();                  // drains vmcnt -> LDS tiles ready
    s16x8 af[4], bf[4];
#pragma unroll
    for (int mi = 0; mi < 4; mi++)
      af[mi] = *(const s16x8*)&lA[(wr * 64 + mi * 16 + l16) * 32 + q * 8];
#pragma unroll
    for (int ni = 0; ni < 4; ni++)
      bf[ni] = *(const s16x8*)&lB[(wc * 64 + ni * 16 + l16) * 32 + q * 8];
#pragma unroll
    for (int mi = 0; mi < 4; mi++)
#pragma unroll
      for (int ni = 0; ni < 4; ni++)
        acc[mi][ni] = __builtin_amdgcn_mfma_f32_16x16x32_bf16(af[mi], bf[ni], acc[mi][ni], 0, 0, 0);
    __syncthreads();
  }

#pragma unroll
  for (int ni = 0; ni < 4; ni++) {
    const int col = blockN + wc * 64 + ni * 16 + l16;
    const float bv = bias[col];
#pragma unroll
    for (int mi = 0; mi < 4; mi++) {
      const int row = blockM + wr * 64 + mi * 16 + q * 4;
      float* cp = C + (size_t)row * 3072 + col;
      cp[0]        = acc[mi][ni][0] + bv;
      cp[3072]     = acc[mi][ni][1] + bv;
      cp[2 * 3072] = acc[mi][ni][2] + bv;
      cp[3 * 3072] = acc[mi][ni][3] + bv;
    }
  }
}

extern "C" void kernel_launch(void* const* d_in, const int* in_sizes, int n_in,
                              void* d_out, int out_size, void* d_ws, size_t ws_size,
                              hipStream_t stream) {
  const float* x  = (const float*)d_in[0];   // 32768*768
  const float* W1 = (const float*)d_in[1];   // 8*16*134
  const float* W2 = (const float*)d_in[2];   // 134*12*12*134
  const float* W3 = (const float*)d_in[3];   // 134*8*16
  const float* b  = (const float*)d_in[4];   // 3072
  float* out = (float*)d_out;

  char* ws = (char*)d_ws;
  u16* Xb   = (u16*)ws;                              // 50,331,648 B
  u16* Wt   = (u16*)(ws + 50331648);                 //  4,718,592 B
  float* T1 = (float*)(ws + 50331648 + 4718592);     //  9,879,552 B (total ~62 MB)

  xconv_kernel<<<12288, 256, 0, stream>>>(x, Xb);
  a1_kernel<<<dim3(76, 4), 256, 0, stream>>>(W1, W2, T1);
  a2_kernel<<<dim3(128, 12), 128, 0, stream>>>(T1, W3, Wt);
  gemm_kernel<<<dim3(24, 256), 256, 0, stream>>>(Xb, Wt, b, out);
}